// Round 6
// baseline (7840.515 us; speedup 1.0000x reference)
//
#include <hip/hip_runtime.h>

typedef __attribute__((ext_vector_type(8))) short short8;
typedef __attribute__((ext_vector_type(4))) float floatx4;

#define BQ 16
#define LQ 512
#define DM 1024
#define DPROJ 4384
#define KD 2048
#define NWG 128          // scan workgroups
#define NTHR 512         // 8 waves: 0-3 = B (state), 4-7 = A (GEMM)
#define AWG 73           // wgs with A work: 73 x 32 cols = 2336

#define RAWT_SLOT 37376       // 16*2336 u64 (depth-2 ring)
#define MSUM_SLOT 512         // 16*32 u64 (depth-8 ring)

__device__ __forceinline__ float siluf(float x) { return x / (1.f + __expf(-x)); }
__device__ __forceinline__ float softplusf(float x) { return (x > 20.f) ? x : log1pf(__expf(x)); }
__device__ __forceinline__ unsigned short f2bf(float f) {
    union { float f; unsigned u; } v; v.f = f;
    unsigned r = v.u + 0x7FFFu + ((v.u >> 16) & 1u);
    return (unsigned short)(r >> 16);
}
__device__ __forceinline__ unsigned long long ld64(const unsigned long long* p) {
    return __hip_atomic_load(p, __ATOMIC_RELAXED, __HIP_MEMORY_SCOPE_AGENT);
}
__device__ __forceinline__ void st64(unsigned long long* p, unsigned long long v) {
    __hip_atomic_store(p, v, __ATOMIC_RELAXED, __HIP_MEMORY_SCOPE_AGENT);
}
__device__ __forceinline__ unsigned long long packf(float f, unsigned e) {
    union { float f; unsigned u; } v; v.f = f;
    return ((unsigned long long)e << 32) | v.u;
}
__device__ __forceinline__ float lof(unsigned long long w) {
    union { unsigned u; float f; } v; v.u = (unsigned)w; return v.f;
}
__device__ __forceinline__ unsigned hie(unsigned long long w) { return (unsigned)(w >> 32); }

// ---------------- fp32 -> bf16 conversion ----------------
__global__ void cvt_bf16_kernel(const float* __restrict__ s, unsigned short* __restrict__ d, int n) {
    int i = blockIdx.x * 256 + threadIdx.x;
    if (i < n) d[i] = f2bf(s[i]);
}

// ---------------- pack [W_rxbc|W_rdt|W_out] -> bf16 [3360][2048] ----------------
__global__ void pack_weights_kernel(const float* __restrict__ rxbc, const float* __restrict__ rdt,
                                    const float* __restrict__ wout, unsigned short* __restrict__ wall) {
    long i = (long)blockIdx.x * 256 + threadIdx.x;
    if (i >= 3360L * KD) return;
    int c = (int)(i >> 11), k = (int)(i & 2047);
    const float* src = (c < 2304) ? rxbc + (long)c * KD + k
                     : (c < 2336) ? rdt + (long)(c - 2304) * KD + k
                     :              wout + (long)(c - 2336) * KD + k;
    wall[i] = f2bf(*src);
}

// ---------------- zero init (grid-stride; NO hipMemsetAsync in capture) ----------
__global__ void setup_zero_kernel(unsigned* __restrict__ z, long nz, unsigned* __restrict__ gh0) {
    long i = (long)blockIdx.x * 256 + threadIdx.x;
    const long stride = (long)gridDim.x * 256;
    for (long k = i; k < nz; k += stride) z[k] = 0u;
    if (i < 16384) gh0[i] = 0u;   // ghist slot 0: 16x2048 bf16 = 16384 u32
}

// ---------------- in_proj GEMM: 128x32 blocks ----------
__global__ __launch_bounds__(256) void gemm_inproj_kernel(const short* __restrict__ A,
                                                          const short* __restrict__ Bw,
                                                          float* __restrict__ C) {
    const int lane = threadIdx.x & 63, wave = threadIdx.x >> 6;
    const int row = lane & 15, q = lane >> 4;
    const long m0 = (long)blockIdx.x * 128 + wave * 16;
    const long n0 = (long)blockIdx.y * 32;
    const short* ap0 = A + (m0 + row) * DM + q * 8;
    const short* ap1 = ap0 + 64 * DM;
    const short* bp0 = Bw + (n0 + row) * DM + q * 8;
    const short* bp1 = bp0 + 16 * DM;
    floatx4 acc00 = {0.f,0.f,0.f,0.f}, acc01 = {0.f,0.f,0.f,0.f};
    floatx4 acc10 = {0.f,0.f,0.f,0.f}, acc11 = {0.f,0.f,0.f,0.f};
    for (int k = 0; k < DM; k += 32) {
        short8 a0 = *(const short8*)(ap0 + k);
        short8 a1 = *(const short8*)(ap1 + k);
        short8 b0 = *(const short8*)(bp0 + k);
        short8 b1 = *(const short8*)(bp1 + k);
        acc00 = __builtin_amdgcn_mfma_f32_16x16x32_bf16(a0, b0, acc00, 0, 0, 0);
        acc01 = __builtin_amdgcn_mfma_f32_16x16x32_bf16(a0, b1, acc01, 0, 0, 0);
        acc10 = __builtin_amdgcn_mfma_f32_16x16x32_bf16(a1, b0, acc10, 0, 0, 0);
        acc11 = __builtin_amdgcn_mfma_f32_16x16x32_bf16(a1, b1, acc11, 0, 0, 0);
    }
    float* cp0 = C + (m0 + q * 4) * DPROJ + n0 + row;
    float* cp1 = cp0 + 64 * DPROJ;
    #pragma unroll
    for (int r = 0; r < 4; ++r) {
        cp0[(long)r * DPROJ]      = acc00[r];
        cp0[(long)r * DPROJ + 16] = acc01[r];
        cp1[(long)r * DPROJ]      = acc10[r];
        cp1[(long)r * DPROJ + 16] = acc11[r];
    }
}

// ---------------- cooperative dataflow scan + fused out-projection ----------------
// Wave-specialized 2-barrier pipeline:
//   waves 4-7 (wgs<73) = A: poll 2 producer flags/lane, load ghist(t), 32 MFMA
//     (K=512/wave, weights streamed from L1/L2), write redu.  No B state.
//   waves 0-3 = B: one wave per head, s[128]/thread (no ypart exchange).
//   Per step: [A work] BAR_A [all: reduce -> tagged rawT(t); B: poll rawT+msum,
//   conv, stage bc_lds] BAR_B [B: state loop, y, ghist(t+1), drain, flag(t+1),
//   prefetch zx(t+1)].
// Safety: redu WAR ordered by BAR_B(t)->BAR_A(t+1); bc_lds WAR by BAR_A; rawT
// depth-2 WAR certified because every A wg's 4 waves jointly poll ALL 512 B
// flags >= t before storing rawT(t) (flag t implies that wg's rawT(t-2) reads
// completed); msum depth-8 ring with epoch check; chain grounded at zeroed state.
__global__ __launch_bounds__(NTHR, 1) void scan_kernel(
    const float* __restrict__ zx,             // [16][512][4384]
    unsigned long long* __restrict__ rawT,    // [2][16][2336] {f32,epoch}
    unsigned short* __restrict__ ghist,       // [513][16][2048] bf16
    unsigned long long* __restrict__ msum,    // [8][16][32] {f32,epoch}
    unsigned* __restrict__ bar,               // 512 bflagF (stride 32)
    const short* __restrict__ wall,           // [3360][2048] bf16
    float* __restrict__ scale_hist,           // [16][512]
    const float* __restrict__ dt_bias, const float* __restrict__ A_log,
    const float* __restrict__ D_param, const float* __restrict__ norm_w,
    const float* __restrict__ conv_w, const float* __restrict__ conv_b,
    float* __restrict__ out)                  // [16][512][1024]
{
    const int w = blockIdx.x, tid = threadIdx.x;
    const int lane = tid & 63, wv = tid >> 6;

    __shared__ float redu[2][4][16][16];   // 8 KB
    __shared__ float bc_lds[2][128];       // 1 KB

    const bool isB = (wv < 4);
    const bool isA = (wv >= 4) && (w < AWG);
    const int colr = lane & 15, q = lane >> 4;
    const unsigned long long* gq = (const unsigned long long*)ghist;  // 8192 u64/slot

    // ---- A config (waves 4-7) ----
    const int m = isA ? (wv - 4) : 0;          // K-slice index
    const long gqb = (long)colr * 512 + m * 128 + q * 2;
    const short* wp0 = wall + ((long)(w * 32 + colr) * KD + m * 512 + q * 8);
    const short* wp1 = wp0 + 16 * KD;
    // per-lane: 2 producer flags (wgs {b*8+2m, b*8+2m+1}, waves 0-3, all b)
    const unsigned *af0, *af1;
    {
        const int c0 = 2 * lane, c1 = 2 * lane + 1;
        af0 = bar + (((c0 >> 3) * 8 + 2 * m + ((c0 >> 2) & 1)) * 4 + (c0 & 3)) * 32;
        af1 = bar + (((c1 >> 3) * 8 + 2 * m + ((c1 >> 2) & 1)) * 4 + (c1 & 3)) * 32;
    }

    // ---- B config (waves 0-3) ----
    const int b = w >> 3, j = w & 7;
    const int h = j * 4 + (wv & 3);            // head (safe 0..31 for all waves)
    float s[128];
    #pragma unroll
    for (int i = 0; i < 128; ++i) s[i] = 0.f;
    const float Aneg = -__expf(A_log[h]);
    const float dtb  = dt_bias[h];
    const float Dp   = D_param[h];
    const float nw   = norm_w[h * 64 + lane];
    const int cx = h * 64 + lane;              // x conv channel (= z col)
    const float4 cwx = *(const float4*)(conv_w + cx * 4);
    const float cbx = conv_b[cx];
    const int cbc = 2048 + (tid >> 7) * 128 + (tid & 127);   // B/C channel (tid<256)
    float4 cwbc = {0.f,0.f,0.f,0.f}; float cbbc = 0.f;
    if (isB) { cwbc = *(const float4*)(conv_w + cbc * 4); cbbc = conv_b[cbc]; }
    float xh1 = 0.f, xh2 = 0.f, xh3 = 0.f, bh1 = 0.f, bh2 = 0.f, bh3 = 0.f;
    // zx carries (prefetched 1 step ahead, issued after drain+flag)
    float xq_c = 0.f, zq_c = 0.f, dzq_c = 0.f, bq_c = 0.f;
    if (isB) {
        const long zr0 = ((long)b * LQ) * DPROJ;
        xq_c  = zx[zr0 + 2048 + cx];
        zq_c  = zx[zr0 + cx];
        dzq_c = zx[zr0 + 4352 + h];
        bq_c  = zx[zr0 + 2048 + cbc];
    }

    for (int t = 0; t < LQ; ++t) {
        const unsigned eR = (unsigned)(t + 1);

        // ===== phase 1: A waves =====
        if (isA) {
            while (__hip_atomic_load(af0, __ATOMIC_RELAXED, __HIP_MEMORY_SCOPE_AGENT)
                   < (unsigned)t) {}
            while (__hip_atomic_load(af1, __ATOMIC_RELAXED, __HIP_MEMORY_SCOPE_AGENT)
                   < (unsigned)t) {}
            const long gb0 = (long)t * 8192 + gqb;
            floatx4 acc0 = {0.f,0.f,0.f,0.f}, acc1 = {0.f,0.f,0.f,0.f};
            #pragma unroll
            for (int ks = 0; ks < 16; ++ks) {
                unsigned long long a0 = ld64(gq + gb0 + ks * 8);
                unsigned long long a1 = ld64(gq + gb0 + ks * 8 + 1);
                union { unsigned long long u[2]; short8 s8; } af;
                af.u[0] = a0; af.u[1] = a1;
                short8 b0 = *(const short8*)(wp0 + ks * 32);
                short8 b1 = *(const short8*)(wp1 + ks * 32);
                acc0 = __builtin_amdgcn_mfma_f32_16x16x32_bf16(af.s8, b0, acc0, 0, 0, 0);
                acc1 = __builtin_amdgcn_mfma_f32_16x16x32_bf16(af.s8, b1, acc1, 0, 0, 0);
            }
            #pragma unroll
            for (int r = 0; r < 4; ++r) {
                redu[0][m][q * 4 + r][colr] = acc0[r];
                redu[1][m][q * 4 + r][colr] = acc1[r];
            }
        }
        __syncthreads();   // BAR_A: redu ready; certifies all 512 flags >= t via A waves

        // ===== phase 2 =====
        float xv = 0.f, dt = 0.f, dA = 0.f, zg = 0.f;
        if (w < AWG) {     // reduce + tagged store (all 512 threads, 1 output each)
            const int orow = tid >> 5, ocol = tid & 31;
            float v = 0.f;
            #pragma unroll
            for (int kw = 0; kw < 4; ++kw) v += redu[ocol >> 4][kw][orow][ocol & 15];
            st64(rawT + (long)(t & 1) * RAWT_SLOT + orow * 2336 + w * 32 + ocol,
                 packf(v, eR));
        }
        if (isB) {
            const unsigned long long* rbase = rawT + (long)(t & 1) * RAWT_SLOT + (long)b * 2336;
            unsigned long long xw = ld64(rbase + cx);
            unsigned long long dw = ld64(rbase + 2304 + h);
            unsigned long long bw = ld64(rbase + cbc);
            float mv = 0.f;
            if (lane < 32) {
                const unsigned long long* mp = msum + ((t + 7) & 7) * MSUM_SLOT + b * 32 + lane;
                unsigned long long wd = ld64(mp);
                while (hie(wd) != (unsigned)t) wd = ld64(mp);
                mv = lof(wd);
            }
            float msv = mv;
            #pragma unroll
            for (int off = 32; off; off >>= 1) msv += __shfl_xor(msv, off, 64);
            const float rs = rsqrtf(msv * (1.f / 2048.f) + 1e-5f);
            if (j == 0 && tid == 0 && t >= 1)
                __hip_atomic_store(scale_hist + b * LQ + (t - 1), rs,
                                   __ATOMIC_RELAXED, __HIP_MEMORY_SCOPE_AGENT);
            while (hie(xw) != eR) xw = ld64(rbase + cx);
            while (hie(dw) != eR) dw = ld64(rbase + 2304 + h);
            while (hie(bw) != eR) bw = ld64(rbase + cbc);
            const float xr = lof(xw), dtrr = lof(dw), bcval = lof(bw);
            float pre = cbbc + bh3 * cwbc.x + bh2 * cwbc.y + bh1 * cwbc.z + bq_c * cwbc.w;
            bc_lds[tid >> 7][tid & 127] = siluf(pre + rs * bcval);
            bh3 = bh2; bh2 = bh1; bh1 = bq_c;
            float xpre = cbx + xh3 * cwx.x + xh2 * cwx.y + xh1 * cwx.z + xq_c * cwx.w;
            xh3 = xh2; xh2 = xh1; xh1 = xq_c;
            xv = siluf(xpre + rs * xr);
            dt = softplusf(siluf(dzq_c + rs * dtrr) + dtb);
            dA = __expf(dt * Aneg);
            zg = siluf(zq_c);
        }
        __syncthreads();   // BAR_B: bc_lds staged

        // ===== phase 3: B waves =====
        if (isB) {
            float dtx = dt * xv, yac = 0.f;
            const floatx4* Bp = (const floatx4*)&bc_lds[0][0];
            const floatx4* Cp = (const floatx4*)&bc_lds[1][0];
            #pragma unroll
            for (int i = 0; i < 32; ++i) {
                floatx4 b4 = Bp[i], c4 = Cp[i];
                s[4*i+0] = s[4*i+0] * dA + dtx * b4.x; yac += s[4*i+0] * c4.x;
                s[4*i+1] = s[4*i+1] * dA + dtx * b4.y; yac += s[4*i+1] * c4.y;
                s[4*i+2] = s[4*i+2] * dA + dtx * b4.z; yac += s[4*i+2] * c4.z;
                s[4*i+3] = s[4*i+3] * dA + dtx * b4.w; yac += s[4*i+3] * c4.w;
            }
            float y = yac + Dp * xv;
            float g = y * zg;
            unsigned gb = (unsigned)f2bf(g * nw);
            unsigned up = __shfl_down(gb, 1);
            if (!(lane & 1))
                __hip_atomic_store((unsigned*)ghist + ((long)(t + 1) * 16384
                                   + ((b * KD + h * 64 + lane) >> 1)),
                                   gb | (up << 16), __ATOMIC_RELAXED, __HIP_MEMORY_SCOPE_AGENT);
            float sq = g * g;
            #pragma unroll
            for (int off = 32; off; off >>= 1) sq += __shfl_xor(sq, off, 64);
            if (lane == 0)
                st64(msum + ((t & 7) * MSUM_SLOT + b * 32 + j * 4 + wv), packf(sq, eR));
            asm volatile("s_waitcnt vmcnt(0)" ::: "memory");   // ghist+msum drain
            if (lane == 0)
                __hip_atomic_store(bar + (w * 4 + wv) * 32, eR,
                                   __ATOMIC_RELAXED, __HIP_MEMORY_SCOPE_AGENT);
            if (t + 1 < LQ) {     // prefetch zx(t+1) AFTER drain (keeps drain cheap)
                const long zr = ((long)b * LQ + (t + 1)) * DPROJ;
                xq_c  = zx[zr + 2048 + cx];
                zq_c  = zx[zr + cx];
                dzq_c = zx[zr + 4352 + h];
                bq_c  = zx[zr + 2048 + cbc];
            }
        }
    }

    // ======== post-loop join + fused out-projection (all 128 wgs) ========
    {
        const unsigned* fp = bar + tid * 32;   // 512 fine bflags, one per thread
        while (__hip_atomic_load(fp, __ATOMIC_RELAXED, __HIP_MEMORY_SCOPE_AGENT) < 512u) {}
    }
    __syncthreads();
    {
        const int vb = w * 2 + (tid >> 8);    // virtual 256-thread block: 0..255
        const int vt = tid & 255;
        const int vwv = vt >> 6, vlane = vt & 63;
        const int vcolr = vlane & 15, vq = vlane >> 4;   // vcolr = batch row of A
        const unsigned long long* gq2 = (const unsigned long long*)ghist;
        for (int it = 0; it < 8; ++it) {
            const int idx = vb * 8 + it;       // 0..2047 = (t, n-block)
            const int tt = idx >> 2;
            const int n0 = (idx & 3) * 256 + vwv * 64;
            const long ab = (long)(tt + 1) * 8192 + vcolr * 512 + vq * 2;
            const short* bp = wall + ((long)(2336 + n0 + vcolr) * KD + vq * 8);
            floatx4 acc0 = {0.f,0.f,0.f,0.f}, acc1 = {0.f,0.f,0.f,0.f};
            floatx4 acc2 = {0.f,0.f,0.f,0.f}, acc3 = {0.f,0.f,0.f,0.f};
            #pragma unroll 4
            for (int kb = 0; kb < 64; ++kb) {
                unsigned long long a0 = ld64(gq2 + ab + kb * 8);
                unsigned long long a1 = ld64(gq2 + ab + kb * 8 + 1);
                union { unsigned long long u[2]; short8 s8; } af;
                af.u[0] = a0; af.u[1] = a1;
                const short* bk = bp + kb * 32;
                acc0 = __builtin_amdgcn_mfma_f32_16x16x32_bf16(af.s8, *(const short8*)(bk),           acc0, 0, 0, 0);
                acc1 = __builtin_amdgcn_mfma_f32_16x16x32_bf16(af.s8, *(const short8*)(bk + 16 * KD), acc1, 0, 0, 0);
                acc2 = __builtin_amdgcn_mfma_f32_16x16x32_bf16(af.s8, *(const short8*)(bk + 32 * KD), acc2, 0, 0, 0);
                acc3 = __builtin_amdgcn_mfma_f32_16x16x32_bf16(af.s8, *(const short8*)(bk + 48 * KD), acc3, 0, 0, 0);
            }
            #pragma unroll
            for (int r = 0; r < 4; ++r) {
                const int bb = vq * 4 + r;     // batch
                float sc;
                if (tt < LQ - 1) {
                    sc = __hip_atomic_load(scale_hist + bb * LQ + tt,
                                           __ATOMIC_RELAXED, __HIP_MEMORY_SCOPE_AGENT);
                } else {
                    // rs(511): msum ring slot 511&7 = 7 (visible post-join)
                    float msv = 0.f;
                    #pragma unroll
                    for (int k = 0; k < 32; ++k)
                        msv += lof(ld64(msum + 7 * MSUM_SLOT + bb * 32 + k));
                    sc = rsqrtf(msv * (1.f / 2048.f) + 1e-5f);
                }
                float* op = out + ((long)bb * LQ + tt) * DM + n0 + vcolr;
                op[0]  = acc0[r] * sc;
                op[16] = acc1[r] * sc;
                op[32] = acc2[r] * sc;
                op[48] = acc3[r] * sc;
            }
        }
    }
}

extern "C" void kernel_launch(void* const* d_in, const int* in_sizes, int n_in,
                              void* d_out, int out_size, void* d_ws, size_t ws_size,
                              hipStream_t stream) {
    const float* u       = (const float*)d_in[0];
    const float* W_in    = (const float*)d_in[1];
    const float* conv_w  = (const float*)d_in[2];
    const float* conv_b  = (const float*)d_in[3];
    const float* W_rxbc  = (const float*)d_in[4];
    const float* W_rdt   = (const float*)d_in[5];
    const float* dt_bias = (const float*)d_in[6];
    const float* A_log   = (const float*)d_in[7];
    const float* D_param = (const float*)d_in[8];
    const float* norm_w  = (const float*)d_in[9];
    const float* W_out   = (const float*)d_in[10];
    float* out = (float*)d_out;

    char* ws = (char*)d_ws;
    size_t off = 0;
    auto alloc = [&](size_t bytes) -> void* {
        void* p = ws + off; off += (bytes + 255) & ~(size_t)255; return p;
    };
    float* zx            = (float*)alloc((size_t)BQ * LQ * DPROJ * 4);        // 143.7 MB
    unsigned short* u_bf = (unsigned short*)alloc((size_t)BQ * LQ * DM * 2);  // reused as wall
    unsigned short* w_bf = (unsigned short*)alloc((size_t)DPROJ * DM * 2);
    unsigned short* gh   = (unsigned short*)alloc((size_t)(LQ + 1) * BQ * KD * 2);  // 33.6 MB
    // contiguous zero-span: [rawT | msum | bar] (sizes are 256-multiples)
    unsigned long long* rawT = (unsigned long long*)alloc((size_t)2 * RAWT_SLOT * 8);  // 598 KB
    unsigned long long* msum = (unsigned long long*)alloc((size_t)8 * MSUM_SLOT * 8);  // 32 KB
    unsigned* bar        = (unsigned*)alloc(16384 * 4);                                // 64 KB
    float* scale_hist    = (float*)alloc((size_t)BQ * LQ * 4);

    const long zero_u32 = ((size_t)2 * RAWT_SLOT * 8 + (size_t)8 * MSUM_SLOT * 8
                           + (size_t)16384 * 4) / 4;
    setup_zero_kernel<<<680, 256, 0, stream>>>((unsigned*)rawT, zero_u32, (unsigned*)gh);

    { int n = BQ * LQ * DM; cvt_bf16_kernel<<<(n + 255) / 256, 256, 0, stream>>>(u, u_bf, n); }
    { int n = DPROJ * DM;   cvt_bf16_kernel<<<(n + 255) / 256, 256, 0, stream>>>(W_in, w_bf, n); }
    gemm_inproj_kernel<<<dim3(BQ * LQ / 128, DPROJ / 32), 256, 0, stream>>>(
        (const short*)u_bf, (const short*)w_bf, zx);
    unsigned short* wall = u_bf;   // dead after GEMM; reuse for packed scan weights
    { long n = 3360L * KD;
      pack_weights_kernel<<<(int)((n + 255) / 256), 256, 0, stream>>>(W_rxbc, W_rdt, W_out, wall); }

    void* args[] = { &zx, &rawT, &gh, &msum, &bar, &wall, &scale_hist,
                     &dt_bias, &A_log, &D_param, &norm_w, &conv_w, &conv_b, &out };
    hipLaunchCooperativeKernel((void*)scan_kernel, dim3(NWG), dim3(NTHR), args, 0, stream);
}